// Round 1
// baseline (232.705 us; speedup 1.0000x reference)
//
#include <hip/hip_runtime.h>
#include <math.h>

// Problem constants: B=128, C=48, H=W=64, p=32, N=4, D=49152
#define PLANE 4096            // 64*64
#define OUT0 25165824         // 128*48*64*64 (flat offset of logdet output)

typedef float fx4 __attribute__((ext_vector_type(4)));

// ws layout (floats):
#define WS_GT   0             // [2304]  GT[k*48+r] = G[r][k]
#define WS_PART 4096          // [128*2*4] score sums per (b, s): {s11,s12,s21,s22}

// ---------------- k0: GT[k][r] = sum_o Wq[o,r]*Wk[o,k] over 3 pairs ----
__global__ void g_kernel(const float* __restrict__ Wq1, const float* __restrict__ Wq2,
                         const float* __restrict__ Wq3, const float* __restrict__ Wk1,
                         const float* __restrict__ Wk2, const float* __restrict__ Wk3,
                         float* __restrict__ GT) {
    int idx = blockIdx.x * 256 + threadIdx.x;
    if (idx >= 2304) return;
    int k = idx / 48, r = idx % 48;   // GT[k*48+r] = G[r][k]
    float acc = 0.f;
    for (int o = 0; o < 48; ++o) {
        acc = fmaf(Wq1[o * 48 + r], Wk1[o * 48 + k], acc);
        acc = fmaf(Wq2[o * 48 + r], Wk2[o * 48 + k], acc);
        acc = fmaf(Wq3[o * 48 + r], Wk3[o * 48 + k], acc);
    }
    GT[idx] = acc;
}

// ---------------- k1: scores, now with coalesced LDS staging ----------
// grid 1024 = b(128) x g(8 row-groups); block 512.
// Stage phase: full rows (both parities, every byte used across s=0/1) loaded as
// float4, parity-compacted into LDS Xc[s][c][row][jj] (48 KB).
// Compute phase: identical r-split quadratic forms as before, t/v from LDS
// broadcast reads (16 unique addrs/wave on 16 distinct banks, conflict-free).
__global__ __launch_bounds__(512) void score_kernel(const float* __restrict__ x,
                                                    const float* __restrict__ GT,
                                                    float* __restrict__ part) {
    __shared__ float Gs[2304];
    __shared__ float Xc[2][48][8][16];   // [s][c][row: 0-3 top, 4-7 bottom][jj]
    __shared__ float red[8][4];
    int tid = threadIdx.x;
    int bid = blockIdx.x;
    int g = bid & 7;
    int b = bid >> 3;

    for (int idx = tid; idx < 2304; idx += 512) Gs[idx] = GT[idx];

    // ---- stage: 6144 fx4 = 48c x 8 rows x 16 fx4 (full 256B rows, coalesced)
    const float* xb = x + (size_t)b * (48 * PLANE);
#pragma unroll
    for (int t = 0; t < 12; ++t) {
        int l = t * 512 + tid;           // 0..6143
        int c = l >> 7;                  // 0..47
        int row = (l >> 4) & 7;          // 0..7 (0-3 top, 4-7 bottom)
        int w4 = l & 15;                 // fx4 index within row
        int h = 4 * g + row + ((row >= 4) ? 28 : 0);   // top: 4g+row, bottom: 4g+32+(row-4)
        fx4 d = *(const fx4*)(xb + c * PLANE + h * 64 + w4 * 4);
        int s = w4 >> 3;                 // left half -> s=0 (even cols), right -> s=1 (odd)
        int w4p = w4 & 7;
        // parity-s elements of this fx4: q=s -> jj=2*w4p ; q=s+2 -> jj=2*w4p+1
        float2 pr;
        pr.x = s ? d[1] : d[0];
        pr.y = s ? d[3] : d[2];
        *(float2*)(&Xc[s][c][row][2 * w4p]) = pr;
    }
    __syncthreads();

    // ---- compute: thread (pix, rc); pix -> (s, local row il, jj)
    int pix = tid >> 2;                  // 0..127
    int rc = tid & 3;                    // r-chunk: rows rc*12 .. rc*12+11
    int s = pix >> 6;
    int il = (pix >> 4) & 3;
    int jj = pix & 15;

    const float* Xt = &Xc[s][0][il][jj];       // stride per k: 8*16 = 128 floats
    const float* Xv = &Xc[s][0][il + 4][jj];

    float u1[12], u2[12], a1[12], a2[12];
#pragma unroll
    for (int j = 0; j < 12; ++j) { u1[j] = 0.f; u2[j] = 0.f; a1[j] = 0.f; a2[j] = 0.f; }

    const fx4* gbase = (const fx4*)(Gs + rc * 12);   // 48B-aligned

#pragma unroll
    for (int k = 0; k < 48; ++k) {
        float t = Xt[k * 128];
        float v = Xv[k * 128];
        fx4 gA = gbase[k * 12 + 0];   // Gs[k*48 + rc*12 + 0..3]
        fx4 gB = gbase[k * 12 + 1];
        fx4 gC = gbase[k * 12 + 2];
#pragma unroll
        for (int j = 0; j < 4; ++j) {
            u1[j]     = fmaf(gA[j], t, u1[j]);
            u2[j]     = fmaf(gA[j], v, u2[j]);
            u1[j + 4] = fmaf(gB[j], t, u1[j + 4]);
            u2[j + 4] = fmaf(gB[j], v, u2[j + 4]);
            u1[j + 8] = fmaf(gC[j], t, u1[j + 8]);
            u2[j + 8] = fmaf(gC[j], v, u2[j + 8]);
        }
        // capture v into this thread's chunk registers when k is in-chunk
        const int q = k / 12, j0 = k % 12;
        bool m = (rc == q);
        a1[j0] = m ? t : a1[j0];
        a2[j0] = m ? v : a2[j0];
    }

    float s11 = 0.f, s12 = 0.f, s21 = 0.f, s22 = 0.f;
#pragma unroll
    for (int j = 0; j < 12; ++j) {
        s11 = fmaf(a1[j], u1[j], s11);
        s12 = fmaf(a1[j], u2[j], s12);
        s21 = fmaf(a2[j], u1[j], s21);
        s22 = fmaf(a2[j], u2[j], s22);
    }

    // full-wave butterfly: sums over 4 r-chunks AND the wave's 16 jj columns
    for (int off = 1; off < 64; off <<= 1) {
        s11 += __shfl_xor(s11, off, 64);
        s12 += __shfl_xor(s12, off, 64);
        s21 += __shfl_xor(s21, off, 64);
        s22 += __shfl_xor(s22, off, 64);
    }
    int wv = tid >> 6;                  // wave = fixed (s = wv>>2, il = wv&3)
    if ((tid & 63) == 0) {
        red[wv][0] = s11; red[wv][1] = s12; red[wv][2] = s21; red[wv][3] = s22;
    }
    __syncthreads();
    if (tid < 8) {
        int so = tid >> 2, j = tid & 3;
        float tot = red[so * 4 + 0][j] + red[so * 4 + 1][j] +
                    red[so * 4 + 2][j] + red[so * 4 + 3][j];
        atomicAdd(&part[(b * 2 + so) * 4 + j], tot);
    }
}

// ---------------- k2: streaming output + fused attn/softmax/logdet ----------------
__global__ __launch_bounds__(256) void out_kernel(const float* __restrict__ x,
                                                  const float* __restrict__ part,
                                                  const float* __restrict__ logdet_in,
                                                  const float* __restrict__ off_p,
                                                  const float* __restrict__ off2_p,
                                                  float* __restrict__ out,
                                                  float* __restrict__ out_logdet) {
    int bc = blockIdx.x;            // 128*48
    int b = bc / 48;

    const float inv_scale = 4.5105361e-3f;   // 1/sqrt(49152)
    float off = off_p[0];
    float c2o = off2_p[0];
    float ld = 0.f;
    float Ad[4], Ao[4];
#pragma unroll
    for (int s = 0; s < 2; ++s) {
        int base = (b * 2 + s) * 4;
        float stt = part[base + 0] * inv_scale;
        float stb = part[base + 1] * inv_scale;
        float sbt = part[base + 2] * inv_scale;
        float sbb = part[base + 3] * inv_scale;

        float m0 = fmaxf(fmaxf(stt, stb), 0.f);
        float e00 = expf(stt - m0), e01 = expf(stb - m0), ez0 = expf(-m0);
        float d0 = e00 + e01 + 2.f * ez0;
        float ptt = e00 / d0, ptb = e01 / d0;
        float m1 = fmaxf(fmaxf(sbt, sbb), 0.f);
        float e10 = expf(sbt - m1), e11 = expf(sbb - m1), ez1 = expf(-m1);
        float d1 = e10 + e11 + 2.f * ez1;
        float pbt = e10 / d1, pbb = e11 / d1;

        float adt = ptt + c2o + off;
        float aot = ptb + c2o;
        float adb = pbb + c2o + off;
        float aob = pbt + c2o;
        Ad[s] = adt; Ao[s] = aot; Ad[s + 2] = adb; Ao[s + 2] = aob;
        float det = adt * adb - aot * aob;
        ld += logf(fabsf(det));
    }
    if ((bc - b * 48) == 0 && threadIdx.x == 0) {
        out_logdet[b] = logdet_in[b] + ld * 24576.0f;
    }

    const fx4* xb4 = (const fx4*)(x + (size_t)bc * PLANE);
    fx4* ob4 = (fx4*)(out + (size_t)bc * PLANE);
    int tid = threadIdx.x;
#pragma unroll
    for (int it = 0; it < 2; ++it) {
        int f = it * 256 + tid;       // 0..511
        int h = f >> 4;               // 0..31
        int w4 = f & 15;
        fx4 xt = xb4[h * 16 + w4];
        fx4 xv = xb4[(h + 32) * 16 + w4];
        int wb = w4 >> 3;
        float Adt = wb ? Ad[1] : Ad[0];
        float Aot = wb ? Ao[1] : Ao[0];
        float Adb = wb ? Ad[3] : Ad[2];
        float Aob = wb ? Ao[3] : Ao[2];

        fx4 rt, rv;
#pragma unroll
        for (int q = 0; q < 4; ++q) {
            int e = (wb + q) & 1;
            float t = xt[q], v = xv[q];
            float mt = fmaf(Adt, t, Aot * v);
            float mv = fmaf(Adb, v, Aob * t);
            rt[q] = e ? mt : t;
            rv[q] = e ? mv : v;
        }
        __builtin_nontemporal_store(rt, &ob4[h * 16 + w4]);
        __builtin_nontemporal_store(rv, &ob4[(h + 32) * 16 + w4]);
    }
}

extern "C" void kernel_launch(void* const* d_in, const int* in_sizes, int n_in,
                              void* d_out, int out_size, void* d_ws, size_t ws_size,
                              hipStream_t stream) {
    const float* x      = (const float*)d_in[0];
    const float* logdet = (const float*)d_in[1];
    const float* Wq1    = (const float*)d_in[2];
    const float* Wq2    = (const float*)d_in[3];
    const float* Wq3    = (const float*)d_in[4];
    const float* Wk1    = (const float*)d_in[5];
    const float* Wk2    = (const float*)d_in[6];
    const float* Wk3    = (const float*)d_in[7];
    const float* off    = (const float*)d_in[8];
    const float* off2   = (const float*)d_in[9];
    // d_in[10] (offset3) is a uniform pre-softmax shift -> cancels; unused.

    float* out = (float*)d_out;
    float* ws  = (float*)d_ws;
    float* GT   = ws + WS_GT;
    float* part = ws + WS_PART;

    hipMemsetAsync(part, 0, 128 * 2 * 4 * sizeof(float), stream);
    g_kernel<<<9, 256, 0, stream>>>(Wq1, Wq2, Wq3, Wk1, Wk2, Wk3, GT);
    score_kernel<<<1024, 512, 0, stream>>>(x, GT, part);
    out_kernel<<<6144, 256, 0, stream>>>(x, part, logdet, off, off2, out, out + OUT0);
}